// Round 1
// baseline (2038.697 us; speedup 1.0000x reference)
//
#include <hip/hip_runtime.h>

typedef unsigned short u16;
typedef __bf16 bf16x8 __attribute__((ext_vector_type(8)));
typedef float f32x4 __attribute__((ext_vector_type(4)));

#define DEV static __device__ __forceinline__

DEV u16 f2bf(float f) {
    unsigned int u = __builtin_bit_cast(unsigned int, f);
    u += 0x7FFFu + ((u >> 16) & 1u);
    return (u16)(u >> 16);
}

DEV bf16x8 frag_ld(const u16* p) {  // p must be 16B aligned
    return __builtin_bit_cast(bf16x8, *(const uint4*)p);
}

// ---------------- tiny setup kernels ----------------
__global__ void kConv(const float* __restrict__ Wk, const float* __restrict__ Wv,
                      u16* __restrict__ Wkv) {
    int id = blockIdx.x * 256 + threadIdx.x;            // 0..131071
    float v = (id < 65536) ? Wk[id] : Wv[id - 65536];
    Wkv[id] = f2bf(v);
}

__global__ void kInit(const float* __restrict__ noise, const float* __restrict__ mean,
                      const float* __restrict__ logv, float* __restrict__ slots) {
    int id = blockIdx.x * 256 + threadIdx.x;            // 0..131071
    int d = id & 255;
    slots[id] = mean[d] + __expf(logv[d]) * noise[id];
}

// ---------------- kA: LN(inputs) fused with k/v projection ----------------
// grid 2048 blocks (b = blk>>5, 128 rows each), 256 threads (4 waves)
__global__ __launch_bounds__(256) void kA(
    const float* __restrict__ X, const float* __restrict__ gin, const float* __restrict__ bin,
    const u16* __restrict__ Wkv, const float* __restrict__ bk, const float* __restrict__ bv,
    u16* __restrict__ Ko, u16* __restrict__ Vo)
{
    __shared__ u16 Al[128 * 264];     // x tile, bf16, row stride 264 (pad 8)
    __shared__ u16 Bl[64 * 264];      // weight tile
    __shared__ u16 Cl[9216];          // epilogue repack: [128][72] or [64][136]
    const int tid = threadIdx.x;
    const int w = tid >> 6, lane = tid & 63;
    const int quad = lane >> 4, l16 = lane & 15;
    const int b = blockIdx.x >> 5;
    const int m0 = (blockIdx.x & 31) << 7;
    const size_t row0 = (size_t)b * 4096 + m0;

    // stage A with LayerNorm: wave w handles rows w*32 .. +31
    {
        const int c = lane << 2;
        const float4 g4 = *(const float4*)(gin + c);
        const float4 b4 = *(const float4*)(bin + c);
        #pragma unroll 4
        for (int i = 0; i < 32; ++i) {
            const int r = w * 32 + i;
            const float4 x = *(const float4*)(X + (row0 + r) * 256 + c);
            float s1 = x.x + x.y + x.z + x.w;
            float s2 = x.x * x.x + x.y * x.y + x.z * x.z + x.w * x.w;
            #pragma unroll
            for (int o = 32; o > 0; o >>= 1) { s1 += __shfl_xor(s1, o); s2 += __shfl_xor(s2, o); }
            const float mu = s1 * (1.f / 256.f);
            const float rs = rsqrtf(s2 * (1.f / 256.f) - mu * mu + 1e-5f);
            ushort4 pk;
            pk.x = f2bf((x.x - mu) * rs * g4.x + b4.x);
            pk.y = f2bf((x.y - mu) * rs * g4.y + b4.y);
            pk.z = f2bf((x.z - mu) * rs * g4.z + b4.z);
            pk.w = f2bf((x.w - mu) * rs * g4.w + b4.w);
            *(ushort4*)(Al + r * 264 + c) = pk;
        }
    }

    for (int nt = 0; nt < 8; ++nt) {
        __syncthreads();   // Bl free (prev mfma done), Cl free (prev stores done)
        #pragma unroll
        for (int it = 0; it < 8; ++it) {
            const int chunk = tid + it * 256;
            const int r = chunk >> 5, cc = (chunk & 31) << 3;
            *(uint4*)(Bl + r * 264 + cc) = *(const uint4*)(Wkv + (size_t)(nt * 64 + r) * 256 + cc);
        }
        __syncthreads();

        f32x4 acc[2][4] = {};
        #pragma unroll
        for (int k0 = 0; k0 < 256; k0 += 32) {
            const bf16x8 a0 = frag_ld(Al + (w * 32 + l16) * 264 + k0 + quad * 8);
            const bf16x8 a1 = frag_ld(Al + (w * 32 + 16 + l16) * 264 + k0 + quad * 8);
            #pragma unroll
            for (int n2 = 0; n2 < 4; ++n2) {
                const bf16x8 bfr = frag_ld(Bl + (n2 * 16 + l16) * 264 + k0 + quad * 8);
                acc[0][n2] = __builtin_amdgcn_mfma_f32_16x16x32_bf16(a0, bfr, acc[0][n2], 0, 0, 0);
                acc[1][n2] = __builtin_amdgcn_mfma_f32_16x16x32_bf16(a1, bfr, acc[1][n2], 0, 0, 0);
            }
        }

        if (nt < 4) {              // k output, normal layout [row][col]
            const int c0 = nt * 64;
            #pragma unroll
            for (int mt = 0; mt < 2; ++mt)
                #pragma unroll
                for (int n2 = 0; n2 < 4; ++n2) {
                    const int cc = n2 * 16 + l16;
                    const float bias = bk[c0 + cc];
                    #pragma unroll
                    for (int rg = 0; rg < 4; ++rg) {
                        const int rr = w * 32 + mt * 16 + quad * 4 + rg;
                        Cl[rr * 72 + cc] = f2bf(acc[mt][n2][rg] + bias);
                    }
                }
            __syncthreads();
            #pragma unroll
            for (int it = 0; it < 4; ++it) {
                const int chunk = tid + it * 256;
                const int r = chunk >> 3, cc = (chunk & 7) << 3;
                *(uint4*)(Ko + (row0 + r) * 256 + c0 + cc) = *(const uint4*)(Cl + r * 72 + cc);
            }
        } else {                   // v output, transposed [d][row]
            const int d0 = (nt - 4) * 64;
            #pragma unroll
            for (int mt = 0; mt < 2; ++mt)
                #pragma unroll
                for (int n2 = 0; n2 < 4; ++n2) {
                    const int cc = n2 * 16 + l16;
                    const int rr = w * 32 + mt * 16 + quad * 4;
                    const float bias = bv[d0 + cc];
                    ushort4 pk;
                    pk.x = f2bf(acc[mt][n2][0] + bias);
                    pk.y = f2bf(acc[mt][n2][1] + bias);
                    pk.z = f2bf(acc[mt][n2][2] + bias);
                    pk.w = f2bf(acc[mt][n2][3] + bias);
                    *(ushort4*)(Cl + cc * 136 + rr) = pk;
                }
            __syncthreads();
            #pragma unroll
            for (int it = 0; it < 4; ++it) {
                const int chunk = tid + it * 256;
                const int cc = chunk >> 4, r8 = (chunk & 15) << 3;
                *(uint4*)(Vo + ((size_t)b * 256 + d0 + cc) * 4096 + m0 + r8) =
                    *(const uint4*)(Cl + cc * 136 + r8);
            }
        }
    }
}

// ---------------- kB1: LN(slots) + q projection (SCALE folded in) ----------------
// grid 512 (b*8+s), 256 threads
__global__ __launch_bounds__(256) void kB1(
    const float* __restrict__ slots, const float* __restrict__ gs, const float* __restrict__ bs,
    const float* __restrict__ Wq, const float* __restrict__ bq, u16* __restrict__ qo)
{
    __shared__ float sn[256];
    __shared__ float red[8];
    const int t = threadIdx.x;
    const int row = blockIdx.x;
    const float x = slots[(size_t)row * 256 + t];
    float s1 = x, s2 = x * x;
    #pragma unroll
    for (int o = 32; o > 0; o >>= 1) { s1 += __shfl_xor(s1, o); s2 += __shfl_xor(s2, o); }
    if ((t & 63) == 0) { red[t >> 6] = s1; red[4 + (t >> 6)] = s2; }
    __syncthreads();
    s1 = red[0] + red[1] + red[2] + red[3];
    s2 = red[4] + red[5] + red[6] + red[7];
    const float mu = s1 * (1.f / 256.f);
    const float rs = rsqrtf(s2 * (1.f / 256.f) - mu * mu + 1e-5f);
    sn[t] = (x - mu) * rs * gs[t] + bs[t];
    __syncthreads();
    float acc = 0.f;
    #pragma unroll 4
    for (int d = 0; d < 256; ++d) acc += Wq[(size_t)t * 256 + d] * sn[d];
    const int b = row >> 3, s = row & 7;
    qo[((size_t)b * 16 + s) * 256 + t] = f2bf((acc + bq[t]) * 0.0625f);
}

// ---------------- kB2: dots -> softmax(slots) -> attn out + updates partials ----------------
// grid (32 n-tiles, 64 b), 256 threads (4 waves)
__global__ __launch_bounds__(256) void kB2(
    const u16* __restrict__ Q, const u16* __restrict__ Kk, const u16* __restrict__ Vt,
    float* __restrict__ attn_out, float* __restrict__ upd)
{
    __shared__ u16 KV[34816];        // k: [128][264] then v: [256][136]
    __shared__ float dsc[8 * 132];
    __shared__ u16 att[16 * 136];
    const int tid = threadIdx.x;
    const int w = tid >> 6, lane = tid & 63;
    const int quad = lane >> 4, l16 = lane & 15;
    const int b = blockIdx.y;
    const int n0 = blockIdx.x << 7;

    #pragma unroll
    for (int it = 0; it < 16; ++it) {   // stage k tile
        const int chunk = tid + it * 256;
        const int r = chunk >> 5, cc = (chunk & 31) << 3;
        *(uint4*)(KV + r * 264 + cc) = *(const uint4*)(Kk + ((size_t)b * 4096 + n0 + r) * 256 + cc);
    }
    __syncthreads();

    f32x4 acc[2] = {};
    const u16* qb = Q + (size_t)b * 16 * 256;
    #pragma unroll
    for (int k0 = 0; k0 < 256; k0 += 32) {
        const bf16x8 a = frag_ld(qb + l16 * 256 + k0 + quad * 8);  // global, L2-hot
        #pragma unroll
        for (int n2 = 0; n2 < 2; ++n2) {
            const bf16x8 bfr = frag_ld(KV + (w * 32 + n2 * 16 + l16) * 264 + k0 + quad * 8);
            acc[n2] = __builtin_amdgcn_mfma_f32_16x16x32_bf16(a, bfr, acc[n2], 0, 0, 0);
        }
    }
    if (quad < 2) {
        #pragma unroll
        for (int n2 = 0; n2 < 2; ++n2)
            #pragma unroll
            for (int rg = 0; rg < 4; ++rg)
                dsc[(quad * 4 + rg) * 132 + w * 32 + n2 * 16 + l16] = acc[n2][rg];
    }
    __syncthreads();

    if (tid < 128) {                   // softmax over the 8 slots for column j
        const int j = tid;
        float v0[8], mx = -1e30f;
        #pragma unroll
        for (int i = 0; i < 8; ++i) { v0[i] = dsc[i * 132 + j]; mx = fmaxf(mx, v0[i]); }
        float sum = 0.f;
        #pragma unroll
        for (int i = 0; i < 8; ++i) { v0[i] = __expf(v0[i] - mx); sum += v0[i]; }
        const float inv = 1.f / sum;
        #pragma unroll
        for (int i = 0; i < 8; ++i) {
            const float a = v0[i] * inv + 1e-8f;
            attn_out[((size_t)b * 8 + i) * 4096 + n0 + j] = a;
            att[i * 136 + j] = f2bf(a);
        }
    }
    #pragma unroll
    for (int it = 0; it < 16; ++it) {   // stage v tile (overwrites k region; safe: barrier above)
        const int chunk = tid + it * 256;
        const int r = chunk >> 4, cc = (chunk & 15) << 3;
        *(uint4*)(KV + r * 136 + cc) = *(const uint4*)(Vt + ((size_t)b * 256 + r) * 4096 + n0 + cc);
    }
    __syncthreads();

    f32x4 ua[4] = {};
    #pragma unroll
    for (int k0 = 0; k0 < 128; k0 += 32) {
        const bf16x8 a = frag_ld(att + l16 * 136 + k0 + quad * 8);
        #pragma unroll
        for (int n2 = 0; n2 < 4; ++n2) {
            const bf16x8 bfr = frag_ld(KV + (w * 64 + n2 * 16 + l16) * 136 + k0 + quad * 8);
            ua[n2] = __builtin_amdgcn_mfma_f32_16x16x32_bf16(a, bfr, ua[n2], 0, 0, 0);
        }
    }
    if (quad < 2) {
        #pragma unroll
        for (int n2 = 0; n2 < 4; ++n2)
            #pragma unroll
            for (int rg = 0; rg < 4; ++rg)
                atomicAdd(upd + ((size_t)b * 8 + quad * 4 + rg) * 256 + w * 64 + n2 * 16 + l16,
                          ua[n2][rg]);
    }
}

// ---------------- kB3: GRU cell + LN + MLP residual, one (b,s) row per block ----------------
__global__ __launch_bounds__(256) void kB3(
    const float* __restrict__ upd, const float* __restrict__ sl_in,
    const float* __restrict__ Wih, const float* __restrict__ bih,
    const float* __restrict__ Whh, const float* __restrict__ bhh,
    const float* __restrict__ W1, const float* __restrict__ b1,
    const float* __restrict__ W2, const float* __restrict__ b2,
    const float* __restrict__ gf, const float* __restrict__ bff,
    float* __restrict__ sl_out)
{
    __shared__ float U[256], S[256], Xs[256], red[8];
    const int t = threadIdx.x;
    const size_t row = blockIdx.x;
    U[t] = upd[row * 256 + t];
    S[t] = sl_in[row * 256 + t];
    __syncthreads();
    float ir = 0, iz = 0, inn = 0, hr = 0, hz = 0, hn = 0;
    #pragma unroll 2
    for (int d = 0; d < 256; ++d) {
        const float uv = U[d], sv = S[d];
        ir  += Wih[(size_t)t * 256 + d] * uv;
        iz  += Wih[(size_t)(256 + t) * 256 + d] * uv;
        inn += Wih[(size_t)(512 + t) * 256 + d] * uv;
        hr  += Whh[(size_t)t * 256 + d] * sv;
        hz  += Whh[(size_t)(256 + t) * 256 + d] * sv;
        hn  += Whh[(size_t)(512 + t) * 256 + d] * sv;
    }
    const float r = 1.f / (1.f + __expf(-(ir + bih[t] + hr + bhh[t])));
    const float z = 1.f / (1.f + __expf(-(iz + bih[256 + t] + hz + bhh[256 + t])));
    const float nn = tanhf(inn + bih[512 + t] + r * (hn + bhh[512 + t]));
    const float hnew = (1.f - z) * nn + z * S[t];
    float s1 = hnew, s2 = hnew * hnew;
    #pragma unroll
    for (int o = 32; o > 0; o >>= 1) { s1 += __shfl_xor(s1, o); s2 += __shfl_xor(s2, o); }
    __syncthreads();                        // all reads of U,S done
    if ((t & 63) == 0) { red[t >> 6] = s1; red[4 + (t >> 6)] = s2; }
    __syncthreads();
    s1 = red[0] + red[1] + red[2] + red[3];
    s2 = red[4] + red[5] + red[6] + red[7];
    const float mu = s1 * (1.f / 256.f);
    const float rsd = rsqrtf(s2 * (1.f / 256.f) - mu * mu + 1e-5f);
    S[t] = (hnew - mu) * rsd * gf[t] + bff[t];
    __syncthreads();
    float h = 0.f;
    #pragma unroll 4
    for (int d = 0; d < 256; ++d) h += W1[(size_t)t * 256 + d] * S[d];
    h = fmaxf(h + b1[t], 0.f);
    Xs[t] = h;
    __syncthreads();
    float o2 = 0.f;
    #pragma unroll 4
    for (int j = 0; j < 256; ++j) o2 += W2[(size_t)t * 256 + j] * Xs[j];
    sl_out[row * 256 + t] = hnew + o2 + b2[t];
}

// ---------------- launch ----------------
extern "C" void kernel_launch(void* const* d_in, const int* in_sizes, int n_in,
                              void* d_out, int out_size, void* d_ws, size_t ws_size,
                              hipStream_t stream) {
    const float* inputs = (const float*)d_in[0];
    const float* noise  = (const float*)d_in[1];
    const float* smean  = (const float*)d_in[2];
    const float* slogv  = (const float*)d_in[3];
    const float* Wq  = (const float*)d_in[4];
    const float* bq  = (const float*)d_in[5];
    const float* Wk  = (const float*)d_in[6];
    const float* bk  = (const float*)d_in[7];
    const float* Wv  = (const float*)d_in[8];
    const float* bv  = (const float*)d_in[9];
    const float* Wih = (const float*)d_in[10];
    const float* bih = (const float*)d_in[11];
    const float* Whh = (const float*)d_in[12];
    const float* bhh = (const float*)d_in[13];
    const float* W1  = (const float*)d_in[14];
    const float* b1  = (const float*)d_in[15];
    const float* W2  = (const float*)d_in[16];
    const float* b2  = (const float*)d_in[17];
    const float* gin = (const float*)d_in[18];
    const float* bin = (const float*)d_in[19];
    const float* gs  = (const float*)d_in[20];
    const float* bs  = (const float*)d_in[21];
    const float* gf  = (const float*)d_in[22];
    const float* bff = (const float*)d_in[23];

    // workspace layout (needs ~258 MB)
    char* ws = (char*)d_ws;
    u16* Kw     = (u16*)(ws);                          // 134,217,728 B  k bf16 [B,N,D]
    u16* Vtw    = (u16*)(ws + 134217728ull);           // 134,217,728 B  v bf16 [B,D,N]
    u16* Wkvw   = (u16*)(ws + 268435456ull);           //     262,144 B
    u16* Qw     = (u16*)(ws + 268697600ull);           //     524,288 B  q bf16 [B,16,D]
    float* slots = (float*)(ws + 269221888ull);        //     524,288 B
    float* updw  = (float*)(ws + 269746176ull);        //     524,288 B

    float* out = (float*)d_out;
    float* attn_out = out + 131072;                    // [B,S,N] after slots [B,S,D]

    kConv<<<512, 256, 0, stream>>>(Wk, Wv, Wkvw);
    kInit<<<512, 256, 0, stream>>>(noise, smean, slogv, slots);
    kA<<<2048, 256, 0, stream>>>(inputs, gin, bin, Wkvw, bk, bv, Kw, Vtw);
    for (int it = 0; it < 3; ++it) {
        kB1<<<512, 256, 0, stream>>>(slots, gs, bs, Wq, bq, Qw);
        hipMemsetAsync(updw, 0, 524288, stream);
        kB2<<<dim3(32, 64), 256, 0, stream>>>(Qw, Kw, Vtw, attn_out, updw);
        kB3<<<512, 256, 0, stream>>>(updw, slots, Wih, bih, Whh, bhh,
                                     W1, b1, W2, b2, gf, bff,
                                     (it == 2) ? out : slots);
    }
}

// Round 2
// 1236.817 us; speedup vs baseline: 1.6483x; 1.6483x over previous
//
#include <hip/hip_runtime.h>

typedef unsigned short u16;
typedef __bf16 bf16x8 __attribute__((ext_vector_type(8)));
typedef float f32x4 __attribute__((ext_vector_type(4)));

#define DEV static __device__ __forceinline__

DEV u16 f2bf(float f) {
    unsigned int u = __builtin_bit_cast(unsigned int, f);
    u += 0x7FFFu + ((u >> 16) & 1u);
    return (u16)(u >> 16);
}

DEV bf16x8 frag_ld(const u16* p) {  // p must be 16B aligned
    return __builtin_bit_cast(bf16x8, *(const uint4*)p);
}

DEV float sigm(float x) { return 1.f / (1.f + __expf(-x)); }

// ---------------- tiny setup kernels ----------------
__global__ void kConv(const float* __restrict__ Wk, const float* __restrict__ Wv,
                      u16* __restrict__ Wkv) {
    int id = blockIdx.x * 256 + threadIdx.x;            // 0..131071
    float v = (id < 65536) ? Wk[id] : Wv[id - 65536];
    Wkv[id] = f2bf(v);
}

__global__ void kInit(const float* __restrict__ noise, const float* __restrict__ mean,
                      const float* __restrict__ logv, float* __restrict__ slots) {
    int id = blockIdx.x * 256 + threadIdx.x;            // 0..131071
    int d = id & 255;
    slots[id] = mean[d] + __expf(logv[d]) * noise[id];
}

// generic 32x32-tiled transpose: out[C][R] = in[R][C]; grid (C/32, R/32), 256 thr
__global__ void kT(const float* __restrict__ in, float* __restrict__ out, int R, int C) {
    __shared__ float tile[32][33];
    const int tx = threadIdx.x & 31, ty = threadIdx.x >> 5;  // ty 0..7
    const int c0 = blockIdx.x * 32, r0 = blockIdx.y * 32;
    #pragma unroll
    for (int i = 0; i < 4; ++i)
        tile[ty + i * 8][tx] = in[(size_t)(r0 + ty + i * 8) * C + c0 + tx];
    __syncthreads();
    #pragma unroll
    for (int i = 0; i < 4; ++i)
        out[(size_t)(c0 + ty + i * 8) * R + r0 + tx] = tile[tx][ty + i * 8];
}

// ---------------- kA: LN(inputs) fused with k/v projection ----------------
// grid 2048 blocks (b = blk>>5, 128 rows each), 256 threads (4 waves)
__global__ __launch_bounds__(256) void kA(
    const float* __restrict__ X, const float* __restrict__ gin, const float* __restrict__ bin,
    const u16* __restrict__ Wkv, const float* __restrict__ bk, const float* __restrict__ bv,
    u16* __restrict__ Ko, u16* __restrict__ Vo)
{
    __shared__ u16 Al[128 * 264];     // x tile, bf16, row stride 264 (pad 8)
    __shared__ u16 Bl[64 * 264];      // weight tile
    __shared__ u16 Cl[9216];          // epilogue repack: [128][72] or [64][136]
    const int tid = threadIdx.x;
    const int w = tid >> 6, lane = tid & 63;
    const int quad = lane >> 4, l16 = lane & 15;
    const int b = blockIdx.x >> 5;
    const int m0 = (blockIdx.x & 31) << 7;
    const size_t row0 = (size_t)b * 4096 + m0;

    // stage A with LayerNorm: wave w handles rows w*32 .. +31
    {
        const int c = lane << 2;
        const float4 g4 = *(const float4*)(gin + c);
        const float4 b4 = *(const float4*)(bin + c);
        #pragma unroll 4
        for (int i = 0; i < 32; ++i) {
            const int r = w * 32 + i;
            const float4 x = *(const float4*)(X + (row0 + r) * 256 + c);
            float s1 = x.x + x.y + x.z + x.w;
            float s2 = x.x * x.x + x.y * x.y + x.z * x.z + x.w * x.w;
            #pragma unroll
            for (int o = 32; o > 0; o >>= 1) { s1 += __shfl_xor(s1, o); s2 += __shfl_xor(s2, o); }
            const float mu = s1 * (1.f / 256.f);
            const float rs = rsqrtf(s2 * (1.f / 256.f) - mu * mu + 1e-5f);
            ushort4 pk;
            pk.x = f2bf((x.x - mu) * rs * g4.x + b4.x);
            pk.y = f2bf((x.y - mu) * rs * g4.y + b4.y);
            pk.z = f2bf((x.z - mu) * rs * g4.z + b4.z);
            pk.w = f2bf((x.w - mu) * rs * g4.w + b4.w);
            *(ushort4*)(Al + r * 264 + c) = pk;
        }
    }

    for (int nt = 0; nt < 8; ++nt) {
        __syncthreads();   // Bl free (prev mfma done), Cl free (prev stores done)
        #pragma unroll
        for (int it = 0; it < 8; ++it) {
            const int chunk = tid + it * 256;
            const int r = chunk >> 5, cc = (chunk & 31) << 3;
            *(uint4*)(Bl + r * 264 + cc) = *(const uint4*)(Wkv + (size_t)(nt * 64 + r) * 256 + cc);
        }
        __syncthreads();

        f32x4 acc[2][4] = {};
        #pragma unroll
        for (int k0 = 0; k0 < 256; k0 += 32) {
            const bf16x8 a0 = frag_ld(Al + (w * 32 + l16) * 264 + k0 + quad * 8);
            const bf16x8 a1 = frag_ld(Al + (w * 32 + 16 + l16) * 264 + k0 + quad * 8);
            #pragma unroll
            for (int n2 = 0; n2 < 4; ++n2) {
                const bf16x8 bfr = frag_ld(Bl + (n2 * 16 + l16) * 264 + k0 + quad * 8);
                acc[0][n2] = __builtin_amdgcn_mfma_f32_16x16x32_bf16(a0, bfr, acc[0][n2], 0, 0, 0);
                acc[1][n2] = __builtin_amdgcn_mfma_f32_16x16x32_bf16(a1, bfr, acc[1][n2], 0, 0, 0);
            }
        }

        if (nt < 4) {              // k output, normal layout [row][col]
            const int c0 = nt * 64;
            #pragma unroll
            for (int mt = 0; mt < 2; ++mt)
                #pragma unroll
                for (int n2 = 0; n2 < 4; ++n2) {
                    const int cc = n2 * 16 + l16;
                    const float bias = bk[c0 + cc];
                    #pragma unroll
                    for (int rg = 0; rg < 4; ++rg) {
                        const int rr = w * 32 + mt * 16 + quad * 4 + rg;
                        Cl[rr * 72 + cc] = f2bf(acc[mt][n2][rg] + bias);
                    }
                }
            __syncthreads();
            #pragma unroll
            for (int it = 0; it < 4; ++it) {
                const int chunk = tid + it * 256;
                const int r = chunk >> 3, cc = (chunk & 7) << 3;
                *(uint4*)(Ko + (row0 + r) * 256 + c0 + cc) = *(const uint4*)(Cl + r * 72 + cc);
            }
        } else {                   // v output, transposed [d][row]
            const int d0 = (nt - 4) * 64;
            #pragma unroll
            for (int mt = 0; mt < 2; ++mt)
                #pragma unroll
                for (int n2 = 0; n2 < 4; ++n2) {
                    const int cc = n2 * 16 + l16;
                    const int rr = w * 32 + mt * 16 + quad * 4;
                    const float bias = bv[d0 + cc];
                    ushort4 pk;
                    pk.x = f2bf(acc[mt][n2][0] + bias);
                    pk.y = f2bf(acc[mt][n2][1] + bias);
                    pk.z = f2bf(acc[mt][n2][2] + bias);
                    pk.w = f2bf(acc[mt][n2][3] + bias);
                    *(ushort4*)(Cl + cc * 136 + rr) = pk;
                }
            __syncthreads();
            #pragma unroll
            for (int it = 0; it < 4; ++it) {
                const int chunk = tid + it * 256;
                const int cc = chunk >> 4, r8 = (chunk & 15) << 3;
                *(uint4*)(Vo + ((size_t)b * 256 + d0 + cc) * 4096 + m0 + r8) =
                    *(const uint4*)(Cl + cc * 136 + r8);
            }
        }
    }
}

// ---------------- kB1: LN(slots) + q projection, coalesced WqT ----------------
// grid 64 (one batch b, 8 slot rows), 256 threads
__global__ __launch_bounds__(256) void kB1(
    const float* __restrict__ slots, const float* __restrict__ gs, const float* __restrict__ bs,
    const float* __restrict__ WqT, const float* __restrict__ bq, u16* __restrict__ qo)
{
    __shared__ float S[8][256];
    __shared__ float SN[8][256];
    const int t = threadIdx.x;
    const int b = blockIdx.x;
    const int w = t >> 6, lane = t & 63;
    #pragma unroll
    for (int r = 0; r < 8; ++r) S[r][t] = slots[((size_t)b * 8 + r) * 256 + t];
    __syncthreads();
    // wave w normalizes rows 2w, 2w+1
    #pragma unroll
    for (int rr = 0; rr < 2; ++rr) {
        const int r = w * 2 + rr;
        const int c = lane * 4;
        const float4 x = *(const float4*)&S[r][c];
        float s1 = x.x + x.y + x.z + x.w;
        float s2 = x.x * x.x + x.y * x.y + x.z * x.z + x.w * x.w;
        #pragma unroll
        for (int o = 32; o > 0; o >>= 1) { s1 += __shfl_xor(s1, o); s2 += __shfl_xor(s2, o); }
        const float mu = s1 * (1.f / 256.f);
        const float rs = rsqrtf(s2 * (1.f / 256.f) - mu * mu + 1e-5f);
        const float4 g4 = *(const float4*)(gs + c);
        const float4 b4 = *(const float4*)(bs + c);
        SN[r][c + 0] = (x.x - mu) * rs * g4.x + b4.x;
        SN[r][c + 1] = (x.y - mu) * rs * g4.y + b4.y;
        SN[r][c + 2] = (x.z - mu) * rs * g4.z + b4.z;
        SN[r][c + 3] = (x.w - mu) * rs * g4.w + b4.w;
    }
    __syncthreads();
    float acc[8] = {};
    #pragma unroll 2
    for (int d = 0; d < 256; ++d) {
        const float wq = WqT[(size_t)d * 256 + t];      // coalesced
        #pragma unroll
        for (int r = 0; r < 8; ++r) acc[r] += wq * SN[r][d];
    }
    const float bb = bq[t];
    #pragma unroll
    for (int r = 0; r < 8; ++r)
        qo[((size_t)b * 16 + r) * 256 + t] = f2bf((acc[r] + bb) * 0.0625f);
}

// ---------------- kB2: dots -> softmax(slots) -> attn out + updates partials ----------------
// grid (32 n-tiles, 64 b), 256 threads (4 waves)
__global__ __launch_bounds__(256) void kB2(
    const u16* __restrict__ Q, const u16* __restrict__ Kk, const u16* __restrict__ Vt,
    float* __restrict__ attn_out, float* __restrict__ upd)
{
    __shared__ u16 KV[34816];        // k: [128][264] then v: [256][136]
    __shared__ float dsc[8 * 132];
    __shared__ u16 att[16 * 136];
    const int tid = threadIdx.x;
    const int w = tid >> 6, lane = tid & 63;
    const int quad = lane >> 4, l16 = lane & 15;
    const int b = blockIdx.y;
    const int n0 = blockIdx.x << 7;

    #pragma unroll
    for (int it = 0; it < 16; ++it) {   // stage k tile
        const int chunk = tid + it * 256;
        const int r = chunk >> 5, cc = (chunk & 31) << 3;
        *(uint4*)(KV + r * 264 + cc) = *(const uint4*)(Kk + ((size_t)b * 4096 + n0 + r) * 256 + cc);
    }
    __syncthreads();

    f32x4 acc[2] = {};
    const u16* qb = Q + (size_t)b * 16 * 256;
    #pragma unroll
    for (int k0 = 0; k0 < 256; k0 += 32) {
        const bf16x8 a = frag_ld(qb + l16 * 256 + k0 + quad * 8);  // global, L2-hot
        #pragma unroll
        for (int n2 = 0; n2 < 2; ++n2) {
            const bf16x8 bfr = frag_ld(KV + (w * 32 + n2 * 16 + l16) * 264 + k0 + quad * 8);
            acc[n2] = __builtin_amdgcn_mfma_f32_16x16x32_bf16(a, bfr, acc[n2], 0, 0, 0);
        }
    }
    if (quad < 2) {
        #pragma unroll
        for (int n2 = 0; n2 < 2; ++n2)
            #pragma unroll
            for (int rg = 0; rg < 4; ++rg)
                dsc[(quad * 4 + rg) * 132 + w * 32 + n2 * 16 + l16] = acc[n2][rg];
    }
    __syncthreads();

    if (tid < 128) {                   // softmax over the 8 slots for column j
        const int j = tid;
        float v0[8], mx = -1e30f;
        #pragma unroll
        for (int i = 0; i < 8; ++i) { v0[i] = dsc[i * 132 + j]; mx = fmaxf(mx, v0[i]); }
        float sum = 0.f;
        #pragma unroll
        for (int i = 0; i < 8; ++i) { v0[i] = __expf(v0[i] - mx); sum += v0[i]; }
        const float inv = 1.f / sum;
        #pragma unroll
        for (int i = 0; i < 8; ++i) {
            const float a = v0[i] * inv + 1e-8f;
            attn_out[((size_t)b * 8 + i) * 4096 + n0 + j] = a;
            att[i * 136 + j] = f2bf(a);
        }
    }
    #pragma unroll
    for (int it = 0; it < 16; ++it) {   // stage v tile (overwrites k region; safe: barrier above)
        const int chunk = tid + it * 256;
        const int r = chunk >> 4, cc = (chunk & 15) << 3;
        *(uint4*)(KV + r * 136 + cc) = *(const uint4*)(Vt + ((size_t)b * 256 + r) * 4096 + n0 + cc);
    }
    __syncthreads();

    f32x4 ua[4] = {};
    #pragma unroll
    for (int k0 = 0; k0 < 128; k0 += 32) {
        const bf16x8 a = frag_ld(att + l16 * 136 + k0 + quad * 8);
        #pragma unroll
        for (int n2 = 0; n2 < 4; ++n2) {
            const bf16x8 bfr = frag_ld(KV + (w * 64 + n2 * 16 + l16) * 136 + k0 + quad * 8);
            ua[n2] = __builtin_amdgcn_mfma_f32_16x16x32_bf16(a, bfr, ua[n2], 0, 0, 0);
        }
    }
    if (quad < 2) {
        #pragma unroll
        for (int n2 = 0; n2 < 4; ++n2)
            #pragma unroll
            for (int rg = 0; rg < 4; ++rg)
                atomicAdd(upd + ((size_t)b * 8 + quad * 4 + rg) * 256 + w * 64 + n2 * 16 + l16,
                          ua[n2][rg]);
    }
}

// ---------------- kB3: GRU + LN + MLP, 4 rows per block, coalesced transposed weights ----
// grid 128 (4 (b,s) rows each), 256 threads
__global__ __launch_bounds__(256) void kB3(
    const float* __restrict__ upd, const float* __restrict__ sl_in,
    const float* __restrict__ WihT, const float* __restrict__ bih,
    const float* __restrict__ WhhT, const float* __restrict__ bhh,
    const float* __restrict__ W1T, const float* __restrict__ b1,
    const float* __restrict__ W2T, const float* __restrict__ b2,
    const float* __restrict__ gf, const float* __restrict__ bff,
    float* __restrict__ sl_out)
{
    __shared__ float U[4][256], S[4][256], SN[4][256], Xs[4][256];
    const int t = threadIdx.x;
    const int w = t >> 6, lane = t & 63;
    const size_t row0 = (size_t)blockIdx.x * 4;

    #pragma unroll
    for (int r = 0; r < 4; ++r) {
        U[r][t] = upd[(row0 + r) * 256 + t];
        S[r][t] = sl_in[(row0 + r) * 256 + t];
    }
    __syncthreads();

    float ir[4] = {}, iz[4] = {}, in_[4] = {}, hr[4] = {}, hz[4] = {}, hn[4] = {};
    #pragma unroll 2
    for (int d = 0; d < 256; ++d) {
        const float wa = WihT[(size_t)d * 768 + t];
        const float wb = WihT[(size_t)d * 768 + 256 + t];
        const float wc = WihT[(size_t)d * 768 + 512 + t];
        const float we = WhhT[(size_t)d * 768 + t];
        const float wf = WhhT[(size_t)d * 768 + 256 + t];
        const float wg = WhhT[(size_t)d * 768 + 512 + t];
        #pragma unroll
        for (int r = 0; r < 4; ++r) {
            const float uv = U[r][d], sv = S[r][d];
            ir[r] += wa * uv;  iz[r] += wb * uv;  in_[r] += wc * uv;
            hr[r] += we * sv;  hz[r] += wf * sv;  hn[r] += wg * sv;
        }
    }
    const float b_ir = bih[t], b_iz = bih[256 + t], b_in = bih[512 + t];
    const float b_hr = bhh[t], b_hz = bhh[256 + t], b_hn = bhh[512 + t];
    float hnew[4];
    #pragma unroll
    for (int r = 0; r < 4; ++r) {
        const float rg = sigm(ir[r] + b_ir + hr[r] + b_hr);
        const float zg = sigm(iz[r] + b_iz + hz[r] + b_hz);
        const float ng = tanhf(in_[r] + b_in + rg * (hn[r] + b_hn));
        hnew[r] = (1.f - zg) * ng + zg * S[r][t];
    }
    __syncthreads();                       // done reading U
    #pragma unroll
    for (int r = 0; r < 4; ++r) U[r][t] = hnew[r];   // reuse U as Hn
    __syncthreads();
    // wave w normalizes row w
    {
        const int c = lane * 4;
        const float4 x = *(const float4*)&U[w][c];
        float s1 = x.x + x.y + x.z + x.w;
        float s2 = x.x * x.x + x.y * x.y + x.z * x.z + x.w * x.w;
        #pragma unroll
        for (int o = 32; o > 0; o >>= 1) { s1 += __shfl_xor(s1, o); s2 += __shfl_xor(s2, o); }
        const float mu = s1 * (1.f / 256.f);
        const float rs = rsqrtf(s2 * (1.f / 256.f) - mu * mu + 1e-5f);
        const float4 g4 = *(const float4*)(gf + c);
        const float4 b4 = *(const float4*)(bff + c);
        SN[w][c + 0] = (x.x - mu) * rs * g4.x + b4.x;
        SN[w][c + 1] = (x.y - mu) * rs * g4.y + b4.y;
        SN[w][c + 2] = (x.z - mu) * rs * g4.z + b4.z;
        SN[w][c + 3] = (x.w - mu) * rs * g4.w + b4.w;
    }
    __syncthreads();
    float hacc[4] = {};
    #pragma unroll 4
    for (int d = 0; d < 256; ++d) {
        const float w1 = W1T[(size_t)d * 256 + t];       // coalesced
        #pragma unroll
        for (int r = 0; r < 4; ++r) hacc[r] += w1 * SN[r][d];
    }
    const float bb1 = b1[t];
    #pragma unroll
    for (int r = 0; r < 4; ++r) Xs[r][t] = fmaxf(hacc[r] + bb1, 0.f);
    __syncthreads();
    float oacc[4] = {};
    #pragma unroll 4
    for (int j = 0; j < 256; ++j) {
        const float w2 = W2T[(size_t)j * 256 + t];       // coalesced
        #pragma unroll
        for (int r = 0; r < 4; ++r) oacc[r] += w2 * Xs[r][j];
    }
    const float bb2 = b2[t];
    #pragma unroll
    for (int r = 0; r < 4; ++r)
        sl_out[(row0 + r) * 256 + t] = hnew[r] + oacc[r] + bb2;
}

// ---------------- launch ----------------
extern "C" void kernel_launch(void* const* d_in, const int* in_sizes, int n_in,
                              void* d_out, int out_size, void* d_ws, size_t ws_size,
                              hipStream_t stream) {
    const float* inputs = (const float*)d_in[0];
    const float* noise  = (const float*)d_in[1];
    const float* smean  = (const float*)d_in[2];
    const float* slogv  = (const float*)d_in[3];
    const float* Wq  = (const float*)d_in[4];
    const float* bq  = (const float*)d_in[5];
    const float* Wk  = (const float*)d_in[6];
    const float* bk  = (const float*)d_in[7];
    const float* Wv  = (const float*)d_in[8];
    const float* bv  = (const float*)d_in[9];
    const float* Wih = (const float*)d_in[10];
    const float* bih = (const float*)d_in[11];
    const float* Whh = (const float*)d_in[12];
    const float* bhh = (const float*)d_in[13];
    const float* W1  = (const float*)d_in[14];
    const float* b1  = (const float*)d_in[15];
    const float* W2  = (const float*)d_in[16];
    const float* b2  = (const float*)d_in[17];
    const float* gin = (const float*)d_in[18];
    const float* bin = (const float*)d_in[19];
    const float* gs  = (const float*)d_in[20];
    const float* bs  = (const float*)d_in[21];
    const float* gf  = (const float*)d_in[22];
    const float* bff = (const float*)d_in[23];

    // workspace layout (~272.7 MB)
    char* ws = (char*)d_ws;
    u16* Kw      = (u16*)(ws);                          // 134,217,728 B  k bf16 [B,N,D]
    u16* Vtw     = (u16*)(ws + 134217728ull);           // 134,217,728 B  v bf16 [B,D,N]
    u16* Wkvw    = (u16*)(ws + 268435456ull);           //     262,144 B
    u16* Qw      = (u16*)(ws + 268697600ull);           //     524,288 B  q bf16 [B,16,D]
    float* slots = (float*)(ws + 269221888ull);         //     524,288 B
    float* updw  = (float*)(ws + 269746176ull);         //     524,288 B
    float* WqT   = (float*)(ws + 270270464ull);         //     262,144 B
    float* WihT  = (float*)(ws + 270532608ull);         //     786,432 B
    float* WhhT  = (float*)(ws + 271319040ull);         //     786,432 B
    float* W1T   = (float*)(ws + 272105472ull);         //     262,144 B
    float* W2T   = (float*)(ws + 272367616ull);         //     262,144 B

    float* out = (float*)d_out;
    float* attn_out = out + 131072;                     // [B,S,N] after slots [B,S,D]

    kConv<<<512, 256, 0, stream>>>(Wk, Wv, Wkvw);
    kInit<<<512, 256, 0, stream>>>(noise, smean, slogv, slots);
    kT<<<dim3(8, 8),  256, 0, stream>>>(Wq,  WqT,  256, 256);
    kT<<<dim3(8, 24), 256, 0, stream>>>(Wih, WihT, 768, 256);
    kT<<<dim3(8, 24), 256, 0, stream>>>(Whh, WhhT, 768, 256);
    kT<<<dim3(8, 8),  256, 0, stream>>>(W1,  W1T,  256, 256);
    kT<<<dim3(8, 8),  256, 0, stream>>>(W2,  W2T,  256, 256);
    kA<<<2048, 256, 0, stream>>>(inputs, gin, bin, Wkvw, bk, bv, Kw, Vtw);
    for (int it = 0; it < 3; ++it) {
        kB1<<<64, 256, 0, stream>>>(slots, gs, bs, WqT, bq, Qw);
        hipMemsetAsync(updw, 0, 524288, stream);
        kB2<<<dim3(32, 64), 256, 0, stream>>>(Qw, Kw, Vtw, attn_out, updw);
        kB3<<<128, 256, 0, stream>>>(updw, slots, WihT, bih, WhhT, bhh,
                                     W1T, b1, W2T, b2, gf, bff,
                                     (it == 2) ? out : slots);
    }
}

// Round 3
// 1220.164 us; speedup vs baseline: 1.6708x; 1.0136x over previous
//
#include <hip/hip_runtime.h>

typedef unsigned short u16;
typedef __bf16 bf16x8 __attribute__((ext_vector_type(8)));
typedef float f32x4 __attribute__((ext_vector_type(4)));

#define DEV static __device__ __forceinline__

DEV u16 f2bf(float f) {
    unsigned int u = __builtin_bit_cast(unsigned int, f);
    u += 0x7FFFu + ((u >> 16) & 1u);
    return (u16)(u >> 16);
}

DEV bf16x8 frag_ld(const u16* p) {  // p must be 16B aligned
    return __builtin_bit_cast(bf16x8, *(const uint4*)p);
}

DEV float sigm(float x) { return 1.f / (1.f + __expf(-x)); }

// ---------------- tiny setup kernels ----------------
__global__ void kConv(const float* __restrict__ Wk, const float* __restrict__ Wv,
                      u16* __restrict__ Wkv) {
    int id = blockIdx.x * 256 + threadIdx.x;            // 0..131071
    float v = (id < 65536) ? Wk[id] : Wv[id - 65536];
    Wkv[id] = f2bf(v);
}

__global__ void kInit(const float* __restrict__ noise, const float* __restrict__ mean,
                      const float* __restrict__ logv, float* __restrict__ slots) {
    int id = blockIdx.x * 256 + threadIdx.x;            // 0..131071
    int d = id & 255;
    slots[id] = mean[d] + __expf(logv[d]) * noise[id];
}

// generic 32x32-tiled transpose: out[C][R] = in[R][C]; grid (C/32, R/32), 256 thr
__global__ void kT(const float* __restrict__ in, float* __restrict__ out, int R, int C) {
    __shared__ float tile[32][33];
    const int tx = threadIdx.x & 31, ty = threadIdx.x >> 5;  // ty 0..7
    const int c0 = blockIdx.x * 32, r0 = blockIdx.y * 32;
    #pragma unroll
    for (int i = 0; i < 4; ++i)
        tile[ty + i * 8][tx] = in[(size_t)(r0 + ty + i * 8) * C + c0 + tx];
    __syncthreads();
    #pragma unroll
    for (int i = 0; i < 4; ++i)
        out[(size_t)(c0 + ty + i * 8) * R + r0 + tx] = tile[tx][ty + i * 8];
}

// ---------------- kA: LN(inputs) fused with k/v projection ----------------
// grid 2048 blocks (b = blk>>5, 128 rows each), 256 threads (4 waves)
// LDS 76.8 KB -> 2 blocks/CU. Weight B-frags read direct from global (L2-hot).
__global__ __launch_bounds__(256) void kA(
    const float* __restrict__ X, const float* __restrict__ gin, const float* __restrict__ bin,
    const u16* __restrict__ Wkv, const float* __restrict__ bk, const float* __restrict__ bv,
    u16* __restrict__ Ko, u16* __restrict__ Vo)
{
    __shared__ u16 Al[128 * 264];     // x tile, bf16, row stride 264 (pad 8)
    __shared__ u16 Cl[64 * 72];       // epilogue repack, half-tile (mt phases)
    const int tid = threadIdx.x;
    const int w = tid >> 6, lane = tid & 63;
    const int quad = lane >> 4, l16 = lane & 15;
    const int b = blockIdx.x >> 5;
    const int m0 = (blockIdx.x & 31) << 7;
    const size_t row0 = (size_t)b * 4096 + m0;

    // stage A with LayerNorm: wave w handles rows w*32 .. +31
    {
        const int c = lane << 2;
        const float4 g4 = *(const float4*)(gin + c);
        const float4 b4 = *(const float4*)(bin + c);
        #pragma unroll 4
        for (int i = 0; i < 32; ++i) {
            const int r = w * 32 + i;
            const float4 x = *(const float4*)(X + (row0 + r) * 256 + c);
            float s1 = x.x + x.y + x.z + x.w;
            float s2 = x.x * x.x + x.y * x.y + x.z * x.z + x.w * x.w;
            #pragma unroll
            for (int o = 32; o > 0; o >>= 1) { s1 += __shfl_xor(s1, o); s2 += __shfl_xor(s2, o); }
            const float mu = s1 * (1.f / 256.f);
            const float rs = rsqrtf(s2 * (1.f / 256.f) - mu * mu + 1e-5f);
            ushort4 pk;
            pk.x = f2bf((x.x - mu) * rs * g4.x + b4.x);
            pk.y = f2bf((x.y - mu) * rs * g4.y + b4.y);
            pk.z = f2bf((x.z - mu) * rs * g4.z + b4.z);
            pk.w = f2bf((x.w - mu) * rs * g4.w + b4.w);
            *(ushort4*)(Al + r * 264 + c) = pk;
        }
    }
    __syncthreads();

    for (int nt = 0; nt < 8; ++nt) {
        f32x4 acc[2][4] = {};
        const u16* wb = Wkv + (size_t)(nt * 64) * 256;
        #pragma unroll
        for (int k0 = 0; k0 < 256; k0 += 32) {
            const bf16x8 a0 = frag_ld(Al + (w * 32 + l16) * 264 + k0 + quad * 8);
            const bf16x8 a1 = frag_ld(Al + (w * 32 + 16 + l16) * 264 + k0 + quad * 8);
            #pragma unroll
            for (int n2 = 0; n2 < 4; ++n2) {
                const bf16x8 bfr = frag_ld(wb + (n2 * 16 + l16) * 256 + k0 + quad * 8);
                acc[0][n2] = __builtin_amdgcn_mfma_f32_16x16x32_bf16(a0, bfr, acc[0][n2], 0, 0, 0);
                acc[1][n2] = __builtin_amdgcn_mfma_f32_16x16x32_bf16(a1, bfr, acc[1][n2], 0, 0, 0);
            }
        }

        if (nt < 4) {              // k output, normal layout [row][col]
            const int c0 = nt * 64;
            #pragma unroll
            for (int mt = 0; mt < 2; ++mt) {
                __syncthreads();   // Cl free (prev phase's stores done)
                #pragma unroll
                for (int n2 = 0; n2 < 4; ++n2) {
                    const int cc = n2 * 16 + l16;
                    const float bias = bk[c0 + cc];
                    #pragma unroll
                    for (int rg = 0; rg < 4; ++rg)
                        Cl[(w * 16 + quad * 4 + rg) * 72 + cc] = f2bf(acc[mt][n2][rg] + bias);
                }
                __syncthreads();
                #pragma unroll
                for (int it = 0; it < 2; ++it) {
                    const int chunk = tid + it * 256;           // 512 chunks
                    const int lr = chunk >> 3, cc8 = (chunk & 7) << 3;
                    const size_t gr = row0 + ((lr >> 4) << 5) + mt * 16 + (lr & 15);
                    *(uint4*)(Ko + gr * 256 + c0 + cc8) = *(const uint4*)(Cl + lr * 72 + cc8);
                }
            }
        } else {                   // v output, transposed [d][row]
            const int d0 = (nt - 4) * 64;
            #pragma unroll
            for (int mt = 0; mt < 2; ++mt) {
                __syncthreads();
                #pragma unroll
                for (int n2 = 0; n2 < 4; ++n2) {
                    const int cc = n2 * 16 + l16;
                    const float bias = bv[d0 + cc];
                    ushort4 pk;
                    pk.x = f2bf(acc[mt][n2][0] + bias);
                    pk.y = f2bf(acc[mt][n2][1] + bias);
                    pk.z = f2bf(acc[mt][n2][2] + bias);
                    pk.w = f2bf(acc[mt][n2][3] + bias);
                    *(ushort4*)(Cl + cc * 72 + w * 16 + quad * 4) = pk;
                }
                __syncthreads();
                #pragma unroll
                for (int it = 0; it < 2; ++it) {
                    const int chunk = tid + it * 256;           // 512 chunks
                    const int cc = chunk >> 3, lo = (chunk & 7) << 3;
                    const int ml = ((lo >> 4) << 5) + mt * 16 + (lo & 15);
                    *(uint4*)(Vo + ((size_t)b * 256 + d0 + cc) * 4096 + m0 + ml) =
                        *(const uint4*)(Cl + cc * 72 + lo);
                }
            }
        }
    }
}

// ---------------- kB1: LN(slots) + q projection, 4-way d-split ----------------
// grid (4 seg, 64 b), 256 threads
__global__ __launch_bounds__(256) void kB1(
    const float* __restrict__ slots, const float* __restrict__ gs, const float* __restrict__ bs,
    const float* __restrict__ WqT, const float* __restrict__ bq, u16* __restrict__ qo)
{
    __shared__ float SN[8][256];
    __shared__ float red2[4][8][64];
    const int t = threadIdx.x;
    const int b = blockIdx.y, seg = blockIdx.x;
    const int w = t >> 6, lane = t & 63;
    // LN: wave w normalizes rows 2w, 2w+1
    #pragma unroll
    for (int rr = 0; rr < 2; ++rr) {
        const int r = w * 2 + rr;
        const int c = lane * 4;
        const float4 x = *(const float4*)(slots + ((size_t)b * 8 + r) * 256 + c);
        float s1 = x.x + x.y + x.z + x.w;
        float s2 = x.x * x.x + x.y * x.y + x.z * x.z + x.w * x.w;
        #pragma unroll
        for (int o = 32; o > 0; o >>= 1) { s1 += __shfl_xor(s1, o); s2 += __shfl_xor(s2, o); }
        const float mu = s1 * (1.f / 256.f);
        const float rs = rsqrtf(s2 * (1.f / 256.f) - mu * mu + 1e-5f);
        const float4 g4 = *(const float4*)(gs + c);
        const float4 b4 = *(const float4*)(bs + c);
        SN[r][c + 0] = (x.x - mu) * rs * g4.x + b4.x;
        SN[r][c + 1] = (x.y - mu) * rs * g4.y + b4.y;
        SN[r][c + 2] = (x.z - mu) * rs * g4.z + b4.z;
        SN[r][c + 3] = (x.w - mu) * rs * g4.w + b4.w;
    }
    __syncthreads();
    const int c = seg * 64 + (t & 63);
    const int p = t >> 6;
    float acc[8] = {};
    #pragma unroll 4
    for (int d = p * 64; d < p * 64 + 64; ++d) {
        const float wq = WqT[(size_t)d * 256 + c];      // coalesced
        #pragma unroll
        for (int r = 0; r < 8; ++r) acc[r] += wq * SN[r][d];
    }
    #pragma unroll
    for (int r = 0; r < 8; ++r) red2[p][r][t & 63] = acc[r];
    __syncthreads();
    const float bb = bq[c];
    #pragma unroll
    for (int rr = t >> 6; rr < 8; rr += 4) {
        const float s = red2[0][rr][t & 63] + red2[1][rr][t & 63]
                      + red2[2][rr][t & 63] + red2[3][rr][t & 63];
        qo[((size_t)b * 16 + rr) * 256 + c] = f2bf((s + bb) * 0.0625f);
    }
}

// ---------------- kB2: dots -> softmax(slots) -> attn + updates, no k/v staging ----------
// grid (32 n-tiles, 64 b), 256 threads (4 waves); ~9 KB LDS -> high occupancy
__global__ __launch_bounds__(256, 6) void kB2(
    const u16* __restrict__ Q, const u16* __restrict__ Kk, const u16* __restrict__ Vt,
    float* __restrict__ attn_out, float* __restrict__ upd, int write_attn)
{
    __shared__ float dsc[8 * 132];
    __shared__ u16 att[16 * 136];
    const int tid = threadIdx.x;
    const int w = tid >> 6, lane = tid & 63;
    const int quad = lane >> 4, l16 = lane & 15;
    const int b = blockIdx.y;
    const int n0 = blockIdx.x << 7;

    // dots: A = q [16x256] (rows 8..15 unused), B = k rows (direct from global)
    f32x4 acc[2] = {};
    const u16* qb = Q + (size_t)b * 16 * 256;
    const u16* kb = Kk + ((size_t)b * 4096 + n0) * 256;
    #pragma unroll
    for (int k0 = 0; k0 < 256; k0 += 32) {
        const bf16x8 a = frag_ld(qb + l16 * 256 + k0 + quad * 8);
        #pragma unroll
        for (int n2 = 0; n2 < 2; ++n2) {
            const bf16x8 bfr = frag_ld(kb + (size_t)(w * 32 + n2 * 16 + l16) * 256 + k0 + quad * 8);
            acc[n2] = __builtin_amdgcn_mfma_f32_16x16x32_bf16(a, bfr, acc[n2], 0, 0, 0);
        }
    }
    if (quad < 2) {
        #pragma unroll
        for (int n2 = 0; n2 < 2; ++n2)
            #pragma unroll
            for (int rg = 0; rg < 4; ++rg)
                dsc[(quad * 4 + rg) * 132 + w * 32 + n2 * 16 + l16] = acc[n2][rg];
    }
    __syncthreads();

    if (tid < 128) {                   // softmax over the 8 slots for column j
        const int j = tid;
        float v0[8], mx = -1e30f;
        #pragma unroll
        for (int i = 0; i < 8; ++i) { v0[i] = dsc[i * 132 + j]; mx = fmaxf(mx, v0[i]); }
        float sum = 0.f;
        #pragma unroll
        for (int i = 0; i < 8; ++i) { v0[i] = __expf(v0[i] - mx); sum += v0[i]; }
        const float inv = 1.f / sum;
        #pragma unroll
        for (int i = 0; i < 8; ++i) {
            const float a = v0[i] * inv + 1e-8f;
            if (write_attn) attn_out[((size_t)b * 8 + i) * 4096 + n0 + j] = a;
            att[i * 136 + j] = f2bf(a);
        }
    }
    __syncthreads();

    // updates: A = att [16x128] (rows 8..15 unused), B = v^T rows (direct from global)
    f32x4 ua[4] = {};
    const u16* vb = Vt + (size_t)b * 256 * 4096 + n0;
    #pragma unroll
    for (int k0 = 0; k0 < 128; k0 += 32) {
        const bf16x8 a = frag_ld(att + l16 * 136 + k0 + quad * 8);
        #pragma unroll
        for (int n2 = 0; n2 < 4; ++n2) {
            const bf16x8 bfr = frag_ld(vb + (size_t)(w * 64 + n2 * 16 + l16) * 4096 + k0 + quad * 8);
            ua[n2] = __builtin_amdgcn_mfma_f32_16x16x32_bf16(a, bfr, ua[n2], 0, 0, 0);
        }
    }
    if (quad < 2) {
        #pragma unroll
        for (int n2 = 0; n2 < 4; ++n2)
            #pragma unroll
            for (int rg = 0; rg < 4; ++rg)
                atomicAdd(upd + ((size_t)b * 8 + quad * 4 + rg) * 256 + w * 64 + n2 * 16 + l16,
                          ua[n2][rg]);
    }
}

// ---------------- kB3: GRU + LN + MLP, 4 rows per block, coalesced transposed weights ----
// grid 128 (4 (b,s) rows each), 256 threads
__global__ __launch_bounds__(256) void kB3(
    const float* __restrict__ upd, const float* __restrict__ sl_in,
    const float* __restrict__ WihT, const float* __restrict__ bih,
    const float* __restrict__ WhhT, const float* __restrict__ bhh,
    const float* __restrict__ W1T, const float* __restrict__ b1,
    const float* __restrict__ W2T, const float* __restrict__ b2,
    const float* __restrict__ gf, const float* __restrict__ bff,
    float* __restrict__ sl_out)
{
    __shared__ float U[4][256], S[4][256], SN[4][256], Xs[4][256];
    const int t = threadIdx.x;
    const int w = t >> 6, lane = t & 63;
    const size_t row0 = (size_t)blockIdx.x * 4;

    #pragma unroll
    for (int r = 0; r < 4; ++r) {
        U[r][t] = upd[(row0 + r) * 256 + t];
        S[r][t] = sl_in[(row0 + r) * 256 + t];
    }
    __syncthreads();

    float ir[4] = {}, iz[4] = {}, in_[4] = {}, hr[4] = {}, hz[4] = {}, hn[4] = {};
    #pragma unroll 2
    for (int d = 0; d < 256; ++d) {
        const float wa = WihT[(size_t)d * 768 + t];
        const float wb = WihT[(size_t)d * 768 + 256 + t];
        const float wc = WihT[(size_t)d * 768 + 512 + t];
        const float we = WhhT[(size_t)d * 768 + t];
        const float wf = WhhT[(size_t)d * 768 + 256 + t];
        const float wg = WhhT[(size_t)d * 768 + 512 + t];
        #pragma unroll
        for (int r = 0; r < 4; ++r) {
            const float uv = U[r][d], sv = S[r][d];
            ir[r] += wa * uv;  iz[r] += wb * uv;  in_[r] += wc * uv;
            hr[r] += we * sv;  hz[r] += wf * sv;  hn[r] += wg * sv;
        }
    }
    const float b_ir = bih[t], b_iz = bih[256 + t], b_in = bih[512 + t];
    const float b_hr = bhh[t], b_hz = bhh[256 + t], b_hn = bhh[512 + t];
    float hnew[4];
    #pragma unroll
    for (int r = 0; r < 4; ++r) {
        const float rg = sigm(ir[r] + b_ir + hr[r] + b_hr);
        const float zg = sigm(iz[r] + b_iz + hz[r] + b_hz);
        const float ng = tanhf(in_[r] + b_in + rg * (hn[r] + b_hn));
        hnew[r] = (1.f - zg) * ng + zg * S[r][t];
    }
    __syncthreads();                       // done reading U
    #pragma unroll
    for (int r = 0; r < 4; ++r) U[r][t] = hnew[r];   // reuse U as Hn
    __syncthreads();
    // wave w normalizes row w
    {
        const int c = lane * 4;
        const float4 x = *(const float4*)&U[w][c];
        float s1 = x.x + x.y + x.z + x.w;
        float s2 = x.x * x.x + x.y * x.y + x.z * x.z + x.w * x.w;
        #pragma unroll
        for (int o = 32; o > 0; o >>= 1) { s1 += __shfl_xor(s1, o); s2 += __shfl_xor(s2, o); }
        const float mu = s1 * (1.f / 256.f);
        const float rs = rsqrtf(s2 * (1.f / 256.f) - mu * mu + 1e-5f);
        const float4 g4 = *(const float4*)(gf + c);
        const float4 b4 = *(const float4*)(bff + c);
        SN[w][c + 0] = (x.x - mu) * rs * g4.x + b4.x;
        SN[w][c + 1] = (x.y - mu) * rs * g4.y + b4.y;
        SN[w][c + 2] = (x.z - mu) * rs * g4.z + b4.z;
        SN[w][c + 3] = (x.w - mu) * rs * g4.w + b4.w;
    }
    __syncthreads();
    float hacc[4] = {};
    #pragma unroll 4
    for (int d = 0; d < 256; ++d) {
        const float w1 = W1T[(size_t)d * 256 + t];       // coalesced
        #pragma unroll
        for (int r = 0; r < 4; ++r) hacc[r] += w1 * SN[r][d];
    }
    const float bb1 = b1[t];
    #pragma unroll
    for (int r = 0; r < 4; ++r) Xs[r][t] = fmaxf(hacc[r] + bb1, 0.f);
    __syncthreads();
    float oacc[4] = {};
    #pragma unroll 4
    for (int j = 0; j < 256; ++j) {
        const float w2 = W2T[(size_t)j * 256 + t];       // coalesced
        #pragma unroll
        for (int r = 0; r < 4; ++r) oacc[r] += w2 * Xs[r][j];
    }
    const float bb2 = b2[t];
    #pragma unroll
    for (int r = 0; r < 4; ++r)
        sl_out[(row0 + r) * 256 + t] = hnew[r] + oacc[r] + bb2;
}

// ---------------- launch ----------------
extern "C" void kernel_launch(void* const* d_in, const int* in_sizes, int n_in,
                              void* d_out, int out_size, void* d_ws, size_t ws_size,
                              hipStream_t stream) {
    const float* inputs = (const float*)d_in[0];
    const float* noise  = (const float*)d_in[1];
    const float* smean  = (const float*)d_in[2];
    const float* slogv  = (const float*)d_in[3];
    const float* Wq  = (const float*)d_in[4];
    const float* bq  = (const float*)d_in[5];
    const float* Wk  = (const float*)d_in[6];
    const float* bk  = (const float*)d_in[7];
    const float* Wv  = (const float*)d_in[8];
    const float* bv  = (const float*)d_in[9];
    const float* Wih = (const float*)d_in[10];
    const float* bih = (const float*)d_in[11];
    const float* Whh = (const float*)d_in[12];
    const float* bhh = (const float*)d_in[13];
    const float* W1  = (const float*)d_in[14];
    const float* b1  = (const float*)d_in[15];
    const float* W2  = (const float*)d_in[16];
    const float* b2  = (const float*)d_in[17];
    const float* gin = (const float*)d_in[18];
    const float* bin = (const float*)d_in[19];
    const float* gs  = (const float*)d_in[20];
    const float* bs  = (const float*)d_in[21];
    const float* gf  = (const float*)d_in[22];
    const float* bff = (const float*)d_in[23];

    // workspace layout (~272.7 MB)
    char* ws = (char*)d_ws;
    u16* Kw      = (u16*)(ws);                          // 134,217,728 B  k bf16 [B,N,D]
    u16* Vtw     = (u16*)(ws + 134217728ull);           // 134,217,728 B  v bf16 [B,D,N]
    u16* Wkvw    = (u16*)(ws + 268435456ull);           //     262,144 B
    u16* Qw      = (u16*)(ws + 268697600ull);           //     524,288 B  q bf16 [B,16,D]
    float* slots = (float*)(ws + 269221888ull);         //     524,288 B
    float* updw  = (float*)(ws + 269746176ull);         //     524,288 B
    float* WqT   = (float*)(ws + 270270464ull);         //     262,144 B
    float* WihT  = (float*)(ws + 270532608ull);         //     786,432 B
    float* WhhT  = (float*)(ws + 271319040ull);         //     786,432 B
    float* W1T   = (float*)(ws + 272105472ull);         //     262,144 B
    float* W2T   = (float*)(ws + 272367616ull);         //     262,144 B

    float* out = (float*)d_out;
    float* attn_out = out + 131072;                     // [B,S,N] after slots [B,S,D]

    kConv<<<512, 256, 0, stream>>>(Wk, Wv, Wkvw);
    kInit<<<512, 256, 0, stream>>>(noise, smean, slogv, slots);
    kT<<<dim3(8, 8),  256, 0, stream>>>(Wq,  WqT,  256, 256);
    kT<<<dim3(8, 24), 256, 0, stream>>>(Wih, WihT, 768, 256);
    kT<<<dim3(8, 24), 256, 0, stream>>>(Whh, WhhT, 768, 256);
    kT<<<dim3(8, 8),  256, 0, stream>>>(W1,  W1T,  256, 256);
    kT<<<dim3(8, 8),  256, 0, stream>>>(W2,  W2T,  256, 256);
    kA<<<2048, 256, 0, stream>>>(inputs, gin, bin, Wkvw, bk, bv, Kw, Vtw);
    for (int it = 0; it < 3; ++it) {
        kB1<<<dim3(4, 64), 256, 0, stream>>>(slots, gs, bs, WqT, bq, Qw);
        hipMemsetAsync(updw, 0, 524288, stream);
        kB2<<<dim3(32, 64), 256, 0, stream>>>(Qw, Kw, Vtw, attn_out, updw, it == 2);
        kB3<<<128, 256, 0, stream>>>(updw, slots, WihT, bih, WhhT, bhh,
                                     W1T, b1, W2T, b2, gf, bff,
                                     (it == 2) ? out : slots);
    }
}

// Round 4
// 1180.088 us; speedup vs baseline: 1.7276x; 1.0340x over previous
//
#include <hip/hip_runtime.h>

typedef unsigned short u16;
typedef __bf16 bf16x8 __attribute__((ext_vector_type(8)));
typedef float f32x4 __attribute__((ext_vector_type(4)));

#define DEV static __device__ __forceinline__

DEV u16 f2bf(float f) {
    unsigned int u = __builtin_bit_cast(unsigned int, f);
    u += 0x7FFFu + ((u >> 16) & 1u);
    return (u16)(u >> 16);
}

DEV bf16x8 frag_ld(const u16* p) {  // p must be 16B aligned
    return __builtin_bit_cast(bf16x8, *(const uint4*)p);
}

DEV float sigm(float x) { return 1.f / (1.f + __expf(-x)); }

// ---------------- tiny setup kernels ----------------
__global__ void kConv(const float* __restrict__ Wk, const float* __restrict__ Wv,
                      u16* __restrict__ Wkv) {
    int id = blockIdx.x * 256 + threadIdx.x;            // 0..131071
    float v = (id < 65536) ? Wk[id] : Wv[id - 65536];
    Wkv[id] = f2bf(v);
}

__global__ void kInit(const float* __restrict__ noise, const float* __restrict__ mean,
                      const float* __restrict__ logv, float* __restrict__ slots) {
    int id = blockIdx.x * 256 + threadIdx.x;            // 0..131071
    int d = id & 255;
    slots[id] = mean[d] + __expf(logv[d]) * noise[id];
}

// generic 32x32-tiled transpose: out[C][R] = in[R][C]; grid (C/32, R/32), 256 thr
__global__ void kT(const float* __restrict__ in, float* __restrict__ out, int R, int C) {
    __shared__ float tile[32][33];
    const int tx = threadIdx.x & 31, ty = threadIdx.x >> 5;  // ty 0..7
    const int c0 = blockIdx.x * 32, r0 = blockIdx.y * 32;
    #pragma unroll
    for (int i = 0; i < 4; ++i)
        tile[ty + i * 8][tx] = in[(size_t)(r0 + ty + i * 8) * C + c0 + tx];
    __syncthreads();
    #pragma unroll
    for (int i = 0; i < 4; ++i)
        out[(size_t)(c0 + ty + i * 8) * R + r0 + tx] = tile[tx][ty + i * 8];
}

// ---------------- kA: LN(inputs) fused with k/v projection (R1 structure) ----------------
// grid 2048 blocks (b = blk>>5, 128 rows each), 256 threads (4 waves)
__global__ __launch_bounds__(256) void kA(
    const float* __restrict__ X, const float* __restrict__ gin, const float* __restrict__ bin,
    const u16* __restrict__ Wkv, const float* __restrict__ bk, const float* __restrict__ bv,
    u16* __restrict__ Ko, u16* __restrict__ Vo)
{
    __shared__ u16 Al[128 * 264];     // x tile, bf16, row stride 264 (pad 8)
    __shared__ u16 Bl[64 * 264];      // weight tile
    __shared__ u16 Cl[9216];          // epilogue repack: [128][72] or [64][136]
    const int tid = threadIdx.x;
    const int w = tid >> 6, lane = tid & 63;
    const int quad = lane >> 4, l16 = lane & 15;
    const int b = blockIdx.x >> 5;
    const int m0 = (blockIdx.x & 31) << 7;
    const size_t row0 = (size_t)b * 4096 + m0;

    // stage A with LayerNorm: wave w handles rows w*32 .. +31
    {
        const int c = lane << 2;
        const float4 g4 = *(const float4*)(gin + c);
        const float4 b4 = *(const float4*)(bin + c);
        #pragma unroll 4
        for (int i = 0; i < 32; ++i) {
            const int r = w * 32 + i;
            const float4 x = *(const float4*)(X + (row0 + r) * 256 + c);
            float s1 = x.x + x.y + x.z + x.w;
            float s2 = x.x * x.x + x.y * x.y + x.z * x.z + x.w * x.w;
            #pragma unroll
            for (int o = 32; o > 0; o >>= 1) { s1 += __shfl_xor(s1, o); s2 += __shfl_xor(s2, o); }
            const float mu = s1 * (1.f / 256.f);
            const float rs = rsqrtf(s2 * (1.f / 256.f) - mu * mu + 1e-5f);
            ushort4 pk;
            pk.x = f2bf((x.x - mu) * rs * g4.x + b4.x);
            pk.y = f2bf((x.y - mu) * rs * g4.y + b4.y);
            pk.z = f2bf((x.z - mu) * rs * g4.z + b4.z);
            pk.w = f2bf((x.w - mu) * rs * g4.w + b4.w);
            *(ushort4*)(Al + r * 264 + c) = pk;
        }
    }

    for (int nt = 0; nt < 8; ++nt) {
        __syncthreads();   // Bl free (prev mfma done), Cl free (prev stores done)
        #pragma unroll
        for (int it = 0; it < 8; ++it) {
            const int chunk = tid + it * 256;
            const int r = chunk >> 5, cc = (chunk & 31) << 3;
            *(uint4*)(Bl + r * 264 + cc) = *(const uint4*)(Wkv + (size_t)(nt * 64 + r) * 256 + cc);
        }
        __syncthreads();

        f32x4 acc[2][4] = {};
        #pragma unroll
        for (int k0 = 0; k0 < 256; k0 += 32) {
            const bf16x8 a0 = frag_ld(Al + (w * 32 + l16) * 264 + k0 + quad * 8);
            const bf16x8 a1 = frag_ld(Al + (w * 32 + 16 + l16) * 264 + k0 + quad * 8);
            #pragma unroll
            for (int n2 = 0; n2 < 4; ++n2) {
                const bf16x8 bfr = frag_ld(Bl + (n2 * 16 + l16) * 264 + k0 + quad * 8);
                acc[0][n2] = __builtin_amdgcn_mfma_f32_16x16x32_bf16(a0, bfr, acc[0][n2], 0, 0, 0);
                acc[1][n2] = __builtin_amdgcn_mfma_f32_16x16x32_bf16(a1, bfr, acc[1][n2], 0, 0, 0);
            }
        }

        if (nt < 4) {              // k output, normal layout [row][col]
            const int c0 = nt * 64;
            #pragma unroll
            for (int mt = 0; mt < 2; ++mt)
                #pragma unroll
                for (int n2 = 0; n2 < 4; ++n2) {
                    const int cc = n2 * 16 + l16;
                    const float bias = bk[c0 + cc];
                    #pragma unroll
                    for (int rg = 0; rg < 4; ++rg) {
                        const int rr = w * 32 + mt * 16 + quad * 4 + rg;
                        Cl[rr * 72 + cc] = f2bf(acc[mt][n2][rg] + bias);
                    }
                }
            __syncthreads();
            #pragma unroll
            for (int it = 0; it < 4; ++it) {
                const int chunk = tid + it * 256;
                const int r = chunk >> 3, cc = (chunk & 7) << 3;
                *(uint4*)(Ko + (row0 + r) * 256 + c0 + cc) = *(const uint4*)(Cl + r * 72 + cc);
            }
        } else {                   // v output, transposed [d][row]
            const int d0 = (nt - 4) * 64;
            #pragma unroll
            for (int mt = 0; mt < 2; ++mt)
                #pragma unroll
                for (int n2 = 0; n2 < 4; ++n2) {
                    const int cc = n2 * 16 + l16;
                    const int rr = w * 32 + mt * 16 + quad * 4;
                    const float bias = bv[d0 + cc];
                    ushort4 pk;
                    pk.x = f2bf(acc[mt][n2][0] + bias);
                    pk.y = f2bf(acc[mt][n2][1] + bias);
                    pk.z = f2bf(acc[mt][n2][2] + bias);
                    pk.w = f2bf(acc[mt][n2][3] + bias);
                    *(ushort4*)(Cl + cc * 136 + rr) = pk;
                }
            __syncthreads();
            #pragma unroll
            for (int it = 0; it < 4; ++it) {
                const int chunk = tid + it * 256;
                const int cc = chunk >> 4, r8 = (chunk & 15) << 3;
                *(uint4*)(Vo + ((size_t)b * 256 + d0 + cc) * 4096 + m0 + r8) =
                    *(const uint4*)(Cl + cc * 136 + r8);
            }
        }
    }
}

// ---------------- kB1: LN(slots) + q projection, 4-way d-split ----------------
// grid (4 seg, 64 b), 256 threads
__global__ __launch_bounds__(256) void kB1(
    const float* __restrict__ slots, const float* __restrict__ gs, const float* __restrict__ bs,
    const float* __restrict__ WqT, const float* __restrict__ bq, u16* __restrict__ qo)
{
    __shared__ float SN[8][256];
    __shared__ float red2[4][8][64];
    const int t = threadIdx.x;
    const int b = blockIdx.y, seg = blockIdx.x;
    const int w = t >> 6, lane = t & 63;
    // LN: wave w normalizes rows 2w, 2w+1
    #pragma unroll
    for (int rr = 0; rr < 2; ++rr) {
        const int r = w * 2 + rr;
        const int c = lane * 4;
        const float4 x = *(const float4*)(slots + ((size_t)b * 8 + r) * 256 + c);
        float s1 = x.x + x.y + x.z + x.w;
        float s2 = x.x * x.x + x.y * x.y + x.z * x.z + x.w * x.w;
        #pragma unroll
        for (int o = 32; o > 0; o >>= 1) { s1 += __shfl_xor(s1, o); s2 += __shfl_xor(s2, o); }
        const float mu = s1 * (1.f / 256.f);
        const float rs = rsqrtf(s2 * (1.f / 256.f) - mu * mu + 1e-5f);
        const float4 g4 = *(const float4*)(gs + c);
        const float4 b4 = *(const float4*)(bs + c);
        SN[r][c + 0] = (x.x - mu) * rs * g4.x + b4.x;
        SN[r][c + 1] = (x.y - mu) * rs * g4.y + b4.y;
        SN[r][c + 2] = (x.z - mu) * rs * g4.z + b4.z;
        SN[r][c + 3] = (x.w - mu) * rs * g4.w + b4.w;
    }
    __syncthreads();
    const int c = seg * 64 + (t & 63);
    const int p = t >> 6;
    float acc[8] = {};
    #pragma unroll 4
    for (int d = p * 64; d < p * 64 + 64; ++d) {
        const float wq = WqT[(size_t)d * 256 + c];      // coalesced
        #pragma unroll
        for (int r = 0; r < 8; ++r) acc[r] += wq * SN[r][d];
    }
    #pragma unroll
    for (int r = 0; r < 8; ++r) red2[p][r][t & 63] = acc[r];
    __syncthreads();
    const float bb = bq[c];
    #pragma unroll
    for (int rr = t >> 6; rr < 8; rr += 4) {
        const float s = red2[0][rr][t & 63] + red2[1][rr][t & 63]
                      + red2[2][rr][t & 63] + red2[3][rr][t & 63];
        qo[((size_t)b * 16 + rr) * 256 + c] = f2bf((s + bb) * 0.0625f);
    }
}

// ---------------- kB2: dots -> softmax(slots) -> attn + per-tile update partials ----------
// grid (32 n-tiles, 64 b), 256 threads (4 waves); ~9 KB LDS, NO atomics
__global__ __launch_bounds__(256, 6) void kB2(
    const u16* __restrict__ Q, const u16* __restrict__ Kk, const u16* __restrict__ Vt,
    float* __restrict__ attn_out, float* __restrict__ part, int write_attn)
{
    __shared__ float dsc[8 * 132];
    __shared__ u16 att[16 * 136];
    const int tid = threadIdx.x;
    const int w = tid >> 6, lane = tid & 63;
    const int quad = lane >> 4, l16 = lane & 15;
    const int b = blockIdx.y;
    const int n0 = blockIdx.x << 7;

    // dots: A = q [16x256] (rows 8..15 unused), B = k rows (direct from global)
    f32x4 acc[2] = {};
    const u16* qb = Q + (size_t)b * 16 * 256;
    const u16* kb = Kk + ((size_t)b * 4096 + n0) * 256;
    #pragma unroll
    for (int k0 = 0; k0 < 256; k0 += 32) {
        const bf16x8 a = frag_ld(qb + l16 * 256 + k0 + quad * 8);
        #pragma unroll
        for (int n2 = 0; n2 < 2; ++n2) {
            const bf16x8 bfr = frag_ld(kb + (size_t)(w * 32 + n2 * 16 + l16) * 256 + k0 + quad * 8);
            acc[n2] = __builtin_amdgcn_mfma_f32_16x16x32_bf16(a, bfr, acc[n2], 0, 0, 0);
        }
    }
    if (quad < 2) {
        #pragma unroll
        for (int n2 = 0; n2 < 2; ++n2)
            #pragma unroll
            for (int rg = 0; rg < 4; ++rg)
                dsc[(quad * 4 + rg) * 132 + w * 32 + n2 * 16 + l16] = acc[n2][rg];
    }
    __syncthreads();

    if (tid < 128) {                   // softmax over the 8 slots for column j
        const int j = tid;
        float v0[8], mx = -1e30f;
        #pragma unroll
        for (int i = 0; i < 8; ++i) { v0[i] = dsc[i * 132 + j]; mx = fmaxf(mx, v0[i]); }
        float sum = 0.f;
        #pragma unroll
        for (int i = 0; i < 8; ++i) { v0[i] = __expf(v0[i] - mx); sum += v0[i]; }
        const float inv = 1.f / sum;
        #pragma unroll
        for (int i = 0; i < 8; ++i) {
            const float a = v0[i] * inv + 1e-8f;
            if (write_attn) attn_out[((size_t)b * 8 + i) * 4096 + n0 + j] = a;
            att[i * 136 + j] = f2bf(a);
        }
    }
    __syncthreads();

    // updates: A = att [16x128] (rows 8..15 unused), B = v^T rows (direct from global)
    f32x4 ua[4] = {};
    const u16* vb = Vt + (size_t)b * 256 * 4096 + n0;
    #pragma unroll
    for (int k0 = 0; k0 < 128; k0 += 32) {
        const bf16x8 a = frag_ld(att + l16 * 136 + k0 + quad * 8);
        #pragma unroll
        for (int n2 = 0; n2 < 4; ++n2) {
            const bf16x8 bfr = frag_ld(vb + (size_t)(w * 64 + n2 * 16 + l16) * 4096 + k0 + quad * 8);
            ua[n2] = __builtin_amdgcn_mfma_f32_16x16x32_bf16(a, bfr, ua[n2], 0, 0, 0);
        }
    }
    // private partial region for this (ntile, b): no contention, plain stores
    float* up = part + ((size_t)blockIdx.x * 64 + b) * 2048;   // [32][64][8][256]
    if (quad < 2) {
        #pragma unroll
        for (int n2 = 0; n2 < 4; ++n2)
            #pragma unroll
            for (int rg = 0; rg < 4; ++rg)
                up[(quad * 4 + rg) * 256 + w * 64 + n2 * 16 + l16] = ua[n2][rg];
    }
}

// reduce 32 n-tile partials -> upd [64*8*256]
__global__ __launch_bounds__(256) void kB2r(const float* __restrict__ part,
                                            float* __restrict__ upd) {
    const int id = blockIdx.x * 256 + threadIdx.x;     // 0..131071
    float s = 0.f;
    #pragma unroll 8
    for (int i = 0; i < 32; ++i) s += part[(size_t)i * 131072 + id];
    upd[id] = s;
}

// ---------------- kB3: GRU + LN + MLP, 4 rows per block, coalesced transposed weights ----
// grid 128 (4 (b,s) rows each), 256 threads
__global__ __launch_bounds__(256) void kB3(
    const float* __restrict__ upd, const float* __restrict__ sl_in,
    const float* __restrict__ WihT, const float* __restrict__ bih,
    const float* __restrict__ WhhT, const float* __restrict__ bhh,
    const float* __restrict__ W1T, const float* __restrict__ b1,
    const float* __restrict__ W2T, const float* __restrict__ b2,
    const float* __restrict__ gf, const float* __restrict__ bff,
    float* __restrict__ sl_out)
{
    __shared__ float U[4][256], S[4][256], SN[4][256], Xs[4][256];
    const int t = threadIdx.x;
    const int w = t >> 6, lane = t & 63;
    const size_t row0 = (size_t)blockIdx.x * 4;

    #pragma unroll
    for (int r = 0; r < 4; ++r) {
        U[r][t] = upd[(row0 + r) * 256 + t];
        S[r][t] = sl_in[(row0 + r) * 256 + t];
    }
    __syncthreads();

    float ir[4] = {}, iz[4] = {}, in_[4] = {}, hr[4] = {}, hz[4] = {}, hn[4] = {};
    #pragma unroll 2
    for (int d = 0; d < 256; ++d) {
        const float wa = WihT[(size_t)d * 768 + t];
        const float wb = WihT[(size_t)d * 768 + 256 + t];
        const float wc = WihT[(size_t)d * 768 + 512 + t];
        const float we = WhhT[(size_t)d * 768 + t];
        const float wf = WhhT[(size_t)d * 768 + 256 + t];
        const float wg = WhhT[(size_t)d * 768 + 512 + t];
        #pragma unroll
        for (int r = 0; r < 4; ++r) {
            const float uv = U[r][d], sv = S[r][d];
            ir[r] += wa * uv;  iz[r] += wb * uv;  in_[r] += wc * uv;
            hr[r] += we * sv;  hz[r] += wf * sv;  hn[r] += wg * sv;
        }
    }
    const float b_ir = bih[t], b_iz = bih[256 + t], b_in = bih[512 + t];
    const float b_hr = bhh[t], b_hz = bhh[256 + t], b_hn = bhh[512 + t];
    float hnew[4];
    #pragma unroll
    for (int r = 0; r < 4; ++r) {
        const float rg = sigm(ir[r] + b_ir + hr[r] + b_hr);
        const float zg = sigm(iz[r] + b_iz + hz[r] + b_hz);
        const float ng = tanhf(in_[r] + b_in + rg * (hn[r] + b_hn));
        hnew[r] = (1.f - zg) * ng + zg * S[r][t];
    }
    __syncthreads();                       // done reading U
    #pragma unroll
    for (int r = 0; r < 4; ++r) U[r][t] = hnew[r];   // reuse U as Hn
    __syncthreads();
    // wave w normalizes row w
    {
        const int c = lane * 4;
        const float4 x = *(const float4*)&U[w][c];
        float s1 = x.x + x.y + x.z + x.w;
        float s2 = x.x * x.x + x.y * x.y + x.z * x.z + x.w * x.w;
        #pragma unroll
        for (int o = 32; o > 0; o >>= 1) { s1 += __shfl_xor(s1, o); s2 += __shfl_xor(s2, o); }
        const float mu = s1 * (1.f / 256.f);
        const float rs = rsqrtf(s2 * (1.f / 256.f) - mu * mu + 1e-5f);
        const float4 g4 = *(const float4*)(gf + c);
        const float4 b4 = *(const float4*)(bff + c);
        SN[w][c + 0] = (x.x - mu) * rs * g4.x + b4.x;
        SN[w][c + 1] = (x.y - mu) * rs * g4.y + b4.y;
        SN[w][c + 2] = (x.z - mu) * rs * g4.z + b4.z;
        SN[w][c + 3] = (x.w - mu) * rs * g4.w + b4.w;
    }
    __syncthreads();
    float hacc[4] = {};
    #pragma unroll 4
    for (int d = 0; d < 256; ++d) {
        const float w1 = W1T[(size_t)d * 256 + t];       // coalesced
        #pragma unroll
        for (int r = 0; r < 4; ++r) hacc[r] += w1 * SN[r][d];
    }
    const float bb1 = b1[t];
    #pragma unroll
    for (int r = 0; r < 4; ++r) Xs[r][t] = fmaxf(hacc[r] + bb1, 0.f);
    __syncthreads();
    float oacc[4] = {};
    #pragma unroll 4
    for (int j = 0; j < 256; ++j) {
        const float w2 = W2T[(size_t)j * 256 + t];       // coalesced
        #pragma unroll
        for (int r = 0; r < 4; ++r) oacc[r] += w2 * Xs[r][j];
    }
    const float bb2 = b2[t];
    #pragma unroll
    for (int r = 0; r < 4; ++r)
        sl_out[(row0 + r) * 256 + t] = hnew[r] + oacc[r] + bb2;
}

// ---------------- launch ----------------
extern "C" void kernel_launch(void* const* d_in, const int* in_sizes, int n_in,
                              void* d_out, int out_size, void* d_ws, size_t ws_size,
                              hipStream_t stream) {
    const float* inputs = (const float*)d_in[0];
    const float* noise  = (const float*)d_in[1];
    const float* smean  = (const float*)d_in[2];
    const float* slogv  = (const float*)d_in[3];
    const float* Wq  = (const float*)d_in[4];
    const float* bq  = (const float*)d_in[5];
    const float* Wk  = (const float*)d_in[6];
    const float* bk  = (const float*)d_in[7];
    const float* Wv  = (const float*)d_in[8];
    const float* bv  = (const float*)d_in[9];
    const float* Wih = (const float*)d_in[10];
    const float* bih = (const float*)d_in[11];
    const float* Whh = (const float*)d_in[12];
    const float* bhh = (const float*)d_in[13];
    const float* W1  = (const float*)d_in[14];
    const float* b1  = (const float*)d_in[15];
    const float* W2  = (const float*)d_in[16];
    const float* b2  = (const float*)d_in[17];
    const float* gin = (const float*)d_in[18];
    const float* bin = (const float*)d_in[19];
    const float* gs  = (const float*)d_in[20];
    const float* bs  = (const float*)d_in[21];
    const float* gf  = (const float*)d_in[22];
    const float* bff = (const float*)d_in[23];

    // workspace layout (~289.4 MB)
    char* ws = (char*)d_ws;
    u16* Kw      = (u16*)(ws);                          // 134,217,728 B  k bf16 [B,N,D]
    u16* Vtw     = (u16*)(ws + 134217728ull);           // 134,217,728 B  v bf16 [B,D,N]
    u16* Wkvw    = (u16*)(ws + 268435456ull);           //     262,144 B
    u16* Qw      = (u16*)(ws + 268697600ull);           //     524,288 B  q bf16 [B,16,D]
    float* slots = (float*)(ws + 269221888ull);         //     524,288 B
    float* updw  = (float*)(ws + 269746176ull);         //     524,288 B
    float* WqT   = (float*)(ws + 270270464ull);         //     262,144 B
    float* WihT  = (float*)(ws + 270532608ull);         //     786,432 B
    float* WhhT  = (float*)(ws + 271319040ull);         //     786,432 B
    float* W1T   = (float*)(ws + 272105472ull);         //     262,144 B
    float* W2T   = (float*)(ws + 272367616ull);         //     262,144 B
    float* partw = (float*)(ws + 272629760ull);         //  16,777,216 B  [32][64][8][256]

    float* out = (float*)d_out;
    float* attn_out = out + 131072;                     // [B,S,N] after slots [B,S,D]

    kConv<<<512, 256, 0, stream>>>(Wk, Wv, Wkvw);
    kInit<<<512, 256, 0, stream>>>(noise, smean, slogv, slots);
    kT<<<dim3(8, 8),  256, 0, stream>>>(Wq,  WqT,  256, 256);
    kT<<<dim3(8, 24), 256, 0, stream>>>(Wih, WihT, 768, 256);
    kT<<<dim3(8, 24), 256, 0, stream>>>(Whh, WhhT, 768, 256);
    kT<<<dim3(8, 8),  256, 0, stream>>>(W1,  W1T,  256, 256);
    kT<<<dim3(8, 8),  256, 0, stream>>>(W2,  W2T,  256, 256);
    kA<<<2048, 256, 0, stream>>>(inputs, gin, bin, Wkvw, bk, bv, Kw, Vtw);
    for (int it = 0; it < 3; ++it) {
        kB1<<<dim3(4, 64), 256, 0, stream>>>(slots, gs, bs, WqT, bq, Qw);
        kB2<<<dim3(32, 64), 256, 0, stream>>>(Qw, Kw, Vtw, attn_out, partw, it == 2);
        kB2r<<<512, 256, 0, stream>>>(partw, updw);
        kB3<<<128, 256, 0, stream>>>(updw, slots, WihT, bih, WhhT, bhh,
                                     W1T, b1, W2T, b2, gf, bff,
                                     (it == 2) ? out : slots);
    }
}